// Round 1
// baseline (1838.927 us; speedup 1.0000x reference)
//
#include <hip/hip_runtime.h>
#include <hip/hip_bf16.h>
#include <math.h>

// ---- types ---------------------------------------------------------------
typedef __bf16 bf16x8 __attribute__((ext_vector_type(8)));  // MFMA A/B frag (4 VGPRs)
typedef __bf16 bf16x4 __attribute__((ext_vector_type(4)));
typedef float  f32x4  __attribute__((ext_vector_type(4)));  // MFMA C/D frag

typedef const __attribute__((address_space(1))) void* gas_ptr;
typedef __attribute__((address_space(3))) void*       las_ptr;

__device__ __forceinline__ void gload_lds16(const void* g, void* l) {
  // async global->LDS, 16B per lane; LDS dest = wave-uniform base + lane*16
  __builtin_amdgcn_global_load_lds((gas_ptr)g, (las_ptr)l, 16, 0, 0);
}

// ---- conversion kernels --------------------------------------------------
__global__ void cvt_f32_bf16(const float4* __restrict__ in, bf16x4* __restrict__ out, long n4) {
  long i = (long)blockIdx.x * blockDim.x + threadIdx.x;
  if (i >= n4) return;
  float4 f = in[i];
  bf16x4 o;
  o.x = (__bf16)f.x; o.y = (__bf16)f.y; o.z = (__bf16)f.z; o.w = (__bf16)f.w;
  out[i] = o;
}

__global__ void cvt_i32_bf16(const int4* __restrict__ in, bf16x4* __restrict__ out, long n4) {
  long i = (long)blockIdx.x * blockDim.x + threadIdx.x;
  if (i >= n4) return;
  int4 f = in[i];
  bf16x4 o;
  o.x = (__bf16)(float)f.x; o.y = (__bf16)(float)f.y;
  o.z = (__bf16)(float)f.z; o.w = (__bf16)(float)f.w;
  out[i] = o;
}

// ---- m97-style 128x128 BT GEMM, bf16 MFMA 16x16x32 -----------------------
// A: [M,K] row-major bf16.  B: [N,K] row-major bf16 (i.e. B^T of the math B).
// EPI==0: C = gelu_exact(acc + bias[n]) -> bf16 Cout [M,N]
// EPI==1: C = acc*scale[n] + bias[n]    -> fp32 Cout [M,N]
template <int EPI>
__global__ void __launch_bounds__(256)
gemm_bt(const __bf16* __restrict__ A, const __bf16* __restrict__ B,
        const float* __restrict__ bias, const float* __restrict__ scale,
        void* __restrict__ Cout, int M, int N, int K)
{
  __shared__ __attribute__((aligned(16))) __bf16 sA[128 * 32];
  __shared__ __attribute__((aligned(16))) __bf16 sB[128 * 32];

  const int tid  = threadIdx.x;
  const int wave = tid >> 6;
  const int lane = tid & 63;
  const int bm = blockIdx.y * 128;
  const int bn = blockIdx.x * 128;

  // --- staging: each wave moves 32 rows of A and 32 rows of B per K-tile.
  // one global_load_lds covers 16 rows (4 lanes/row, 8 bf16 = 16B per lane)
  const int sr = wave * 32 + (lane >> 2);   // this lane's row for inst 0
  const int sc = (lane & 3) * 8;            // this lane's col offset (elements)
  const __bf16* gA = A + (size_t)(bm + sr) * K + sc;
  const __bf16* gB = B + (size_t)(bn + sr) * K + sc;
  const size_t rstep16 = (size_t)16 * K;    // +16 rows
  __bf16* lA0 = &sA[(wave * 32) * 32];
  __bf16* lA1 = &sA[(wave * 32 + 16) * 32];
  __bf16* lB0 = &sB[(wave * 32) * 32];
  __bf16* lB1 = &sB[(wave * 32 + 16) * 32];

  // --- fragment geometry: 2x2 waves each own a 64x64 subtile (4x4 MFMA tiles)
  const int fl = lane & 15;
  const int kq = lane >> 4;                 // 0..3
  const int wm = (wave & 1) * 64;
  const int wn = (wave >> 1) * 64;

  f32x4 acc[4][4] = {};

  const int kiters = K >> 5;                // BK = 32
  for (int kt = 0; kt < kiters; ++kt) {
    __syncthreads();                        // protect LDS from prior reads
    gload_lds16(gA,           lA0);
    gload_lds16(gA + rstep16, lA1);
    gload_lds16(gB,           lB0);
    gload_lds16(gB + rstep16, lB1);
    gA += 32; gB += 32;
    __syncthreads();                        // drains vmcnt (compiler-inserted)

    bf16x8 af[4], bv[4];
#pragma unroll
    for (int i = 0; i < 4; ++i) {
      af[i] = *(const bf16x8*)&sA[(wm + i * 16 + fl) * 32 + kq * 8];
      bv[i] = *(const bf16x8*)&sB[(wn + i * 16 + fl) * 32 + kq * 8];
    }
#pragma unroll
    for (int i = 0; i < 4; ++i)
#pragma unroll
      for (int j = 0; j < 4; ++j)
        acc[i][j] = __builtin_amdgcn_mfma_f32_16x16x32_bf16(af[i], bv[j], acc[i][j], 0, 0, 0);
  }

  // --- epilogue: C/D layout col = lane&15, row = (lane>>4)*4 + reg
  if (EPI == 0) {
    __bf16* H = (__bf16*)Cout;
#pragma unroll
    for (int j = 0; j < 4; ++j) {
      const int col = bn + wn + j * 16 + fl;
      const float bvl = bias[col];
#pragma unroll
      for (int i = 0; i < 4; ++i) {
        const int row0 = bm + wm + i * 16 + kq * 4;
#pragma unroll
        for (int r = 0; r < 4; ++r) {
          float v = acc[i][j][r] + bvl;
          v = 0.5f * v * (1.0f + erff(v * 0.70710678118654752f));  // exact GELU
          H[(size_t)(row0 + r) * N + col] = (__bf16)v;
        }
      }
    }
  } else {
    float* O = (float*)Cout;
#pragma unroll
    for (int j = 0; j < 4; ++j) {
      const int col = bn + wn + j * 16 + fl;
      const float sv = scale[col];
      const float bvl = bias[col];
#pragma unroll
      for (int i = 0; i < 4; ++i) {
        const int row0 = bm + wm + i * 16 + kq * 4;
#pragma unroll
        for (int r = 0; r < 4; ++r) {
          O[(size_t)(row0 + r) * N + col] = acc[i][j][r] * sv + bvl;
        }
      }
    }
  }
}

// ---- driver --------------------------------------------------------------
extern "C" void kernel_launch(void* const* d_in, const int* in_sizes, int n_in,
                              void* d_out, int out_size, void* d_ws, size_t ws_size,
                              hipStream_t stream)
{
  const float* x   = (const float*)d_in[0];   // [M, D] (flattened B,S)
  const float* wup = (const float*)d_in[1];   // [DI, D]  == [N,K] for GEMM1
  const float* bup = (const float*)d_in[2];   // [DI]
  const int*   wdq = (const int*)d_in[3];     // [D, DI]  == [N,K] for GEMM2
  const float* wds = (const float*)d_in[4];   // [D]
  const float* bdn = (const float*)d_in[5];   // [D]
  float* out = (float*)d_out;

  const int  DI = in_sizes[2];                // 8192
  const int  D  = in_sizes[4];                // 2048
  const long M  = (long)in_sizes[0] / D;      // 16384

  // workspace layout (all bf16): xb[M*D] | wub[DI*D] | wdb[D*DI] | hb[CH*DI]
  __bf16* xb  = (__bf16*)d_ws;
  __bf16* wub = xb  + (size_t)M * D;
  __bf16* wdb = wub + (size_t)DI * D;
  __bf16* hb  = wdb + (size_t)D * DI;

  const size_t fixed = 2ull * ((size_t)M * D + 2ull * (size_t)DI * D);
  long CH = M;                                // M-chunk size (adaptive to ws_size)
  while (CH > 128 && fixed + 2ull * (size_t)CH * DI > ws_size) CH >>= 1;

  long n4;
  n4 = (long)M * D / 4;
  cvt_f32_bf16<<<(n4 + 255) / 256, 256, 0, stream>>>((const float4*)x, (bf16x4*)xb, n4);
  n4 = (long)DI * D / 4;
  cvt_f32_bf16<<<(n4 + 255) / 256, 256, 0, stream>>>((const float4*)wup, (bf16x4*)wub, n4);
  n4 = (long)D * DI / 4;
  cvt_i32_bf16<<<(n4 + 255) / 256, 256, 0, stream>>>((const int4*)wdq, (bf16x4*)wdb, n4);

  for (long m0 = 0; m0 < M; m0 += CH) {
    dim3 g1(DI / 128, (unsigned)(CH / 128));
    gemm_bt<0><<<g1, dim3(256), 0, stream>>>(xb + m0 * D, wub, bup, nullptr, hb,
                                             (int)CH, DI, D);
    dim3 g2(D / 128, (unsigned)(CH / 128));
    gemm_bt<1><<<g2, dim3(256), 0, stream>>>(hb, wdb, bdn, wds, out + m0 * D,
                                             (int)CH, D, DI);
  }
}

// Round 2
// 1827.441 us; speedup vs baseline: 1.0063x; 1.0063x over previous
//
#include <hip/hip_runtime.h>
#include <hip/hip_bf16.h>
#include <math.h>

// ---- types ---------------------------------------------------------------
typedef __bf16 bf16x8 __attribute__((ext_vector_type(8)));  // MFMA A/B frag (4 VGPRs)
typedef __bf16 bf16x4 __attribute__((ext_vector_type(4)));
typedef float  f32x4  __attribute__((ext_vector_type(4)));  // MFMA C/D frag

typedef const __attribute__((address_space(1))) void* gas_ptr;
typedef __attribute__((address_space(3))) void*       las_ptr;

__device__ __forceinline__ void gload_lds16(const void* g, void* l) {
  // async global->LDS, 16B per lane; LDS dest = wave-uniform base + lane*16
  __builtin_amdgcn_global_load_lds((gas_ptr)g, (las_ptr)l, 16, 0, 0);
}

// ---- conversion kernels --------------------------------------------------
__global__ void cvt_f32_bf16(const float4* __restrict__ in, bf16x4* __restrict__ out, long n4) {
  long i = (long)blockIdx.x * blockDim.x + threadIdx.x;
  if (i >= n4) return;
  float4 f = in[i];
  bf16x4 o;
  o.x = (__bf16)f.x; o.y = (__bf16)f.y; o.z = (__bf16)f.z; o.w = (__bf16)f.w;
  out[i] = o;
}

__global__ void cvt_i32_bf16(const int4* __restrict__ in, bf16x4* __restrict__ out, long n4) {
  long i = (long)blockIdx.x * blockDim.x + threadIdx.x;
  if (i >= n4) return;
  int4 f = in[i];
  bf16x4 o;
  o.x = (__bf16)(float)f.x; o.y = (__bf16)(float)f.y;
  o.z = (__bf16)(float)f.z; o.w = (__bf16)(float)f.w;
  out[i] = o;
}

// ---- m97-style 128x128 BT GEMM, bf16 MFMA 16x16x32, swizzled LDS ---------
// A: [M,K] row-major bf16.  B: [N,K] row-major bf16 (i.e. B^T of the math B).
// LDS swizzle: row r stores global 16B-block kq at position (kq + ((r>>1)&3))&3.
// Staging lane l therefore fetches global block ((l&3) - ((l>>3)&3)) & 3.
// This spreads the 16-lane ds_read_b128 group 2-way over all 32 banks (free)
// instead of 8-way (2.94x serialization) — SQ_LDS_BANK_CONFLICT was 6.7e7.
// EPI==0: C = gelu_exact(acc + bias[n]) -> bf16 Cout [M,N]
// EPI==1: C = acc*scale[n] + bias[n]    -> fp32 Cout [M,N]
template <int EPI>
__global__ void __launch_bounds__(256)
gemm_bt(const __bf16* __restrict__ A, const __bf16* __restrict__ B,
        const float* __restrict__ bias, const float* __restrict__ scale,
        void* __restrict__ Cout, int M, int N, int K)
{
  __shared__ __attribute__((aligned(16))) __bf16 sA[128 * 32];
  __shared__ __attribute__((aligned(16))) __bf16 sB[128 * 32];

  const int tid  = threadIdx.x;
  const int wave = tid >> 6;
  const int lane = tid & 63;
  const int bm = blockIdx.y * 128;
  const int bn = blockIdx.x * 128;

  // --- staging: each wave moves 32 rows of A and 32 rows of B per K-tile.
  // one global_load_lds covers 16 rows (4 lanes/row, 8 bf16 = 16B per lane)
  const int sr = wave * 32 + (lane >> 2);               // this lane's row
  const int swz = ((lane & 3) - ((lane >> 3) & 3)) & 3; // swizzled 16B block
  const int sc = swz * 8;                               // col offset (elements)
  const __bf16* gA = A + (size_t)(bm + sr) * K + sc;
  const __bf16* gB = B + (size_t)(bn + sr) * K + sc;
  const size_t rstep16 = (size_t)16 * K;    // +16 rows
  __bf16* lA0 = &sA[(wave * 32) * 32];
  __bf16* lA1 = &sA[(wave * 32 + 16) * 32];
  __bf16* lB0 = &sB[(wave * 32) * 32];
  __bf16* lB1 = &sB[(wave * 32 + 16) * 32];

  // --- fragment geometry: 2x2 waves each own a 64x64 subtile (4x4 MFMA tiles)
  const int fl = lane & 15;
  const int kq = lane >> 4;                 // 0..3
  const int wm = (wave & 1) * 64;
  const int wn = (wave >> 1) * 64;
  // swizzled read position of this lane's K-quad within its row
  const int rq = ((kq + ((fl >> 1) & 3)) & 3) * 8;

  f32x4 acc[4][4] = {};

  const int kiters = K >> 5;                // BK = 32
  for (int kt = 0; kt < kiters; ++kt) {
    __syncthreads();                        // protect LDS from prior reads
    gload_lds16(gA,           lA0);
    gload_lds16(gA + rstep16, lA1);
    gload_lds16(gB,           lB0);
    gload_lds16(gB + rstep16, lB1);
    gA += 32; gB += 32;
    __syncthreads();                        // drains vmcnt (compiler-inserted)

    bf16x8 af[4], bv[4];
#pragma unroll
    for (int i = 0; i < 4; ++i) {
      af[i] = *(const bf16x8*)&sA[(wm + i * 16 + fl) * 32 + rq];
      bv[i] = *(const bf16x8*)&sB[(wn + i * 16 + fl) * 32 + rq];
    }
#pragma unroll
    for (int i = 0; i < 4; ++i)
#pragma unroll
      for (int j = 0; j < 4; ++j)
        acc[i][j] = __builtin_amdgcn_mfma_f32_16x16x32_bf16(af[i], bv[j], acc[i][j], 0, 0, 0);
  }

  // --- epilogue: C/D layout col = lane&15, row = (lane>>4)*4 + reg
  if (EPI == 0) {
    __bf16* H = (__bf16*)Cout;
#pragma unroll
    for (int j = 0; j < 4; ++j) {
      const int col = bn + wn + j * 16 + fl;
      const float bvl = bias[col];
#pragma unroll
      for (int i = 0; i < 4; ++i) {
        const int row0 = bm + wm + i * 16 + kq * 4;
#pragma unroll
        for (int r = 0; r < 4; ++r) {
          float v = acc[i][j][r] + bvl;
          v = 0.5f * v * (1.0f + erff(v * 0.70710678118654752f));  // exact GELU
          H[(size_t)(row0 + r) * N + col] = (__bf16)v;
        }
      }
    }
  } else {
    float* O = (float*)Cout;
#pragma unroll
    for (int j = 0; j < 4; ++j) {
      const int col = bn + wn + j * 16 + fl;
      const float sv = scale[col];
      const float bvl = bias[col];
#pragma unroll
      for (int i = 0; i < 4; ++i) {
        const int row0 = bm + wm + i * 16 + kq * 4;
#pragma unroll
        for (int r = 0; r < 4; ++r) {
          O[(size_t)(row0 + r) * N + col] = acc[i][j][r] * sv + bvl;
        }
      }
    }
  }
}

// ---- driver --------------------------------------------------------------
extern "C" void kernel_launch(void* const* d_in, const int* in_sizes, int n_in,
                              void* d_out, int out_size, void* d_ws, size_t ws_size,
                              hipStream_t stream)
{
  const float* x   = (const float*)d_in[0];   // [M, D] (flattened B,S)
  const float* wup = (const float*)d_in[1];   // [DI, D]  == [N,K] for GEMM1
  const float* bup = (const float*)d_in[2];   // [DI]
  const int*   wdq = (const int*)d_in[3];     // [D, DI]  == [N,K] for GEMM2
  const float* wds = (const float*)d_in[4];   // [D]
  const float* bdn = (const float*)d_in[5];   // [D]
  float* out = (float*)d_out;

  const int  DI = in_sizes[2];                // 8192
  const int  D  = in_sizes[4];                // 2048
  const long M  = (long)in_sizes[0] / D;      // 16384

  // workspace layout (all bf16): xb[M*D] | wub[DI*D] | wdb[D*DI] | hb[CH*DI]
  __bf16* xb  = (__bf16*)d_ws;
  __bf16* wub = xb  + (size_t)M * D;
  __bf16* wdb = wub + (size_t)DI * D;
  __bf16* hb  = wdb + (size_t)D * DI;

  const size_t fixed = 2ull * ((size_t)M * D + 2ull * (size_t)DI * D);
  long CH = M;                                // M-chunk size (adaptive to ws_size)
  while (CH > 128 && fixed + 2ull * (size_t)CH * DI > ws_size) CH >>= 1;

  long n4;
  n4 = (long)M * D / 4;
  cvt_f32_bf16<<<(n4 + 255) / 256, 256, 0, stream>>>((const float4*)x, (bf16x4*)xb, n4);
  n4 = (long)DI * D / 4;
  cvt_f32_bf16<<<(n4 + 255) / 256, 256, 0, stream>>>((const float4*)wup, (bf16x4*)wub, n4);
  n4 = (long)D * DI / 4;
  cvt_i32_bf16<<<(n4 + 255) / 256, 256, 0, stream>>>((const int4*)wdq, (bf16x4*)wdb, n4);

  for (long m0 = 0; m0 < M; m0 += CH) {
    dim3 g1(DI / 128, (unsigned)(CH / 128));
    gemm_bt<0><<<g1, dim3(256), 0, stream>>>(xb + m0 * D, wub, bup, nullptr, hb,
                                             (int)CH, DI, D);
    dim3 g2(D / 128, (unsigned)(CH / 128));
    gemm_bt<1><<<g2, dim3(256), 0, stream>>>(hb, wdb, bdn, wds, out + m0 * D,
                                             (int)CH, D, DI);
  }
}